// Round 1
// baseline (96.467 us; speedup 1.0000x reference)
//
#include <hip/hip_runtime.h>

#define L_SEQ 4096
#define BATCH 2
#define NHEAD 4
#define DHEAD 32
#define DMODEL 128

typedef __attribute__((ext_vector_type(4))) float floatx4;
typedef __attribute__((ext_vector_type(8))) __bf16 bf16x8;
typedef __attribute__((ext_vector_type(8))) unsigned short ushort8;
typedef __attribute__((ext_vector_type(2))) unsigned short ushort2v;

__device__ __forceinline__ floatx4 MFMA(ushort8 a, ushort8 b, floatx4 c) {
  return __builtin_amdgcn_mfma_f32_16x16x32_bf16(
      __builtin_bit_cast(bf16x8, a), __builtin_bit_cast(bf16x8, b), c, 0, 0, 0);
}

__device__ __forceinline__ unsigned short f2bf(float f) {
  union { float f; unsigned int u; } x; x.f = f;
  unsigned int u = x.u + 0x7fffu + ((x.u >> 16) & 1u);   // RNE truncate
  return (unsigned short)(u >> 16);
}

// ---------------------------------------------------------------------------
// Kernel 1: fused QKV projection.  out = x @ W^T + b  (Q also * 1/sqrt(32))
// Q,K stored [b*4+h][L][32] bf16 ; V stored transposed [b*4+h][32][L] bf16.
// grid (64 l-blocks, 2 batch, 3 matrices), 256 threads.
// ---------------------------------------------------------------------------
#define WLDS 136   // 128 + 8 pad -> 272B row stride, 2-way max bank alias

__global__ __launch_bounds__(256) void proj_kernel(
    const float* __restrict__ xq, const float* __restrict__ xk,
    const float* __restrict__ xv,
    const float* __restrict__ WQ, const float* __restrict__ bQ,
    const float* __restrict__ WK, const float* __restrict__ bK,
    const float* __restrict__ WV, const float* __restrict__ bV,
    unsigned short* __restrict__ Qs, unsigned short* __restrict__ Ks,
    unsigned short* __restrict__ Vt)
{
  __shared__ unsigned short Wl[128 * WLDS];
  __shared__ float bl[128];
  const int mat = blockIdx.z;
  const int b   = blockIdx.y;
  const int l0  = blockIdx.x * 64;
  const float* __restrict__ x    = (mat == 0) ? xq : (mat == 1) ? xk : xv;
  const float* __restrict__ W    = (mat == 0) ? WQ : (mat == 1) ? WK : WV;
  const float* __restrict__ bias = (mat == 0) ? bQ : (mat == 1) ? bK : bV;
  const int tid = threadIdx.x;

  // stage W (f32 -> bf16) into padded LDS
  #pragma unroll
  for (int it = 0; it < 16; ++it) {
    int idx = tid + it * 256;            // float4 index, 4096 total
    int row = idx >> 5;
    int col = (idx & 31) * 4;
    floatx4 v = *(const floatx4*)(W + row * 128 + col);
    unsigned short* dst = Wl + row * WLDS + col;
    dst[0] = f2bf(v[0]); dst[1] = f2bf(v[1]);
    dst[2] = f2bf(v[2]); dst[3] = f2bf(v[3]);
  }
  if (tid < 128) bl[tid] = bias[tid];
  __syncthreads();

  const int w = tid >> 6, lane = tid & 63;
  const int g = lane >> 4, qi = lane & 15;

  // x fragments: lane holds x[l0+16w+qi][kk*32 + 8g .. +7] as bf16x8
  ushort8 xf[4];
  #pragma unroll
  for (int kk = 0; kk < 4; ++kk) {
    const float* src = x + ((size_t)(l0 + w * 16 + qi) * BATCH + b) * DMODEL + kk * 32 + g * 8;
    floatx4 a = *(const floatx4*)src;
    floatx4 c = *(const floatx4*)(src + 4);
    ushort8 f;
    f[0]=f2bf(a[0]); f[1]=f2bf(a[1]); f[2]=f2bf(a[2]); f[3]=f2bf(a[3]);
    f[4]=f2bf(c[0]); f[5]=f2bf(c[1]); f[6]=f2bf(c[2]); f[7]=f2bf(c[3]);
    xf[kk] = f;
  }

  floatx4 acc[8];
  #pragma unroll
  for (int n = 0; n < 8; ++n) acc[n] = (floatx4){0.f, 0.f, 0.f, 0.f};

  #pragma unroll
  for (int kk = 0; kk < 4; ++kk) {
    #pragma unroll
    for (int n = 0; n < 8; ++n) {
      ushort8 wf = *(const ushort8*)(Wl + (n * 16 + qi) * WLDS + kk * 32 + g * 8);
      // Q/K: D[l][c] = x * W^T ; V: D[c][l] = W * x^T (transposed output, same frags)
      acc[n] = (mat == 2) ? MFMA(wf, xf[kk], acc[n]) : MFMA(xf[kk], wf, acc[n]);
    }
  }

  const int hb4 = b * NHEAD;
  if (mat < 2) {
    unsigned short* __restrict__ outp = (mat == 0) ? Qs : Ks;
    const float scale = (mat == 0) ? 0.17677669529663687f : 1.0f;  // 32^-0.5
    #pragma unroll
    for (int n = 0; n < 8; ++n) {
      int c = n * 16 + qi;
      int h = c >> 5, dh = c & 31;
      float bb = bl[c];
      #pragma unroll
      for (int r = 0; r < 4; ++r) {
        int lq = l0 + w * 16 + 4 * g + r;
        float v = (acc[n][r] + bb) * scale;
        outp[((size_t)(hb4 + h) * L_SEQ + lq) * DHEAD + dh] = f2bf(v);
      }
    }
  } else {
    #pragma unroll
    for (int n = 0; n < 8; ++n) {
      #pragma unroll
      for (int r = 0; r < 4; ++r) {
        int cout = n * 16 + 4 * g + r;
        int h = cout >> 5, dh = cout & 31;
        float v = acc[n][r] + bl[cout];
        int lq = l0 + w * 16 + qi;
        Vt[((size_t)(hb4 + h) * DHEAD + dh) * L_SEQ + lq] = f2bf(v);
      }
    }
  }
}

// ---------------------------------------------------------------------------
// Kernel 2: flash attention over block-causal mask (64-aligned blocks -> no
// element masking). Grid: 8 head-planes x 32 balanced pairs (tq = p, 63-p).
// 4 waves, wave w owns 16 q-rows of each chunk. Swapped QK^T: S^T = K·Q^T.
// ---------------------------------------------------------------------------
#define KPAD 40
#define VPAD 72
#define PPAD 72

__global__ __launch_bounds__(256) void attn_kernel(
    const unsigned short* __restrict__ Qs, const unsigned short* __restrict__ Ks,
    const unsigned short* __restrict__ Vt, unsigned short* __restrict__ ctx)
{
  __shared__ unsigned short Klds[64 * KPAD];
  __shared__ unsigned short Vlds[32 * VPAD];
  __shared__ unsigned short Plds[4 * 16 * PPAD];

  const int bid = blockIdx.x;
  const int hb  = bid >> 5;          // b*4 + h
  const int p   = bid & 31;
  const int tqa = p, tqb = 63 - p;
  const int tid = threadIdx.x;
  const int w = tid >> 6, lane = tid & 63;
  const int g = lane >> 4, qi = lane & 15;
  const int bb = hb >> 2, hh = hb & 3;

  const unsigned short* __restrict__ Qh = Qs + (size_t)hb * L_SEQ * DHEAD;
  const unsigned short* __restrict__ Kh = Ks + (size_t)hb * L_SEQ * DHEAD;
  const unsigned short* __restrict__ Vh = Vt + (size_t)hb * DHEAD * L_SEQ;

  // Q B-fragments: lane holds Q[qbase+qi][8g..8g+7]
  ushort8 qfa = *(const ushort8*)(Qh + (size_t)(tqa * 64 + w * 16 + qi) * DHEAD + g * 8);
  ushort8 qfb = *(const ushort8*)(Qh + (size_t)(tqb * 64 + w * 16 + qi) * DHEAD + g * 8);

  floatx4 ca[2], cb[2];
  #pragma unroll
  for (int nt = 0; nt < 2; ++nt) { ca[nt] = (floatx4){0,0,0,0}; cb[nt] = (floatx4){0,0,0,0}; }
  float ma = -1e30f, la = 0.f, mb = -1e30f, lb = 0.f;

  unsigned short* Pw = Plds + w * 16 * PPAD;

  const int krow = tid >> 2, kch = (tid & 3) * 8;
  const int vrow = tid >> 3, vch = (tid & 7) * 8;

  ushort8 kf[4];
  ushort8 vf[2][2];

  auto step = [&](ushort8 qf, floatx4 (&cc)[2], float& m, float& l) {
    floatx4 s[4];
    #pragma unroll
    for (int tt = 0; tt < 4; ++tt)
      s[tt] = MFMA(kf[tt], qf, (floatx4){0.f, 0.f, 0.f, 0.f});
    // lane holds S^T[kv = 16tt+4g+r][q = qi]; reduce over kv for fixed q
    float vmax = -1e30f;
    #pragma unroll
    for (int tt = 0; tt < 4; ++tt)
      vmax = fmaxf(vmax, fmaxf(fmaxf(s[tt][0], s[tt][1]), fmaxf(s[tt][2], s[tt][3])));
    vmax = fmaxf(vmax, __shfl_xor(vmax, 16));
    vmax = fmaxf(vmax, __shfl_xor(vmax, 32));
    float mnew = fmaxf(m, vmax);
    float corr = __expf(m - mnew);
    m = mnew;
    float rsum = 0.f;
    #pragma unroll
    for (int tt = 0; tt < 4; ++tt) {
      float p0 = __expf(s[tt][0] - mnew);
      float p1 = __expf(s[tt][1] - mnew);
      float p2 = __expf(s[tt][2] - mnew);
      float p3 = __expf(s[tt][3] - mnew);
      rsum += (p0 + p1) + (p2 + p3);
      ushort2v w0, w1;
      w0[0] = f2bf(p0); w0[1] = f2bf(p1);
      w1[0] = f2bf(p2); w1[1] = f2bf(p3);
      *(ushort2v*)(Pw + qi * PPAD + tt * 16 + g * 4)     = w0;
      *(ushort2v*)(Pw + qi * PPAD + tt * 16 + g * 4 + 2) = w1;
    }
    rsum += __shfl_xor(rsum, 16);
    rsum += __shfl_xor(rsum, 32);
    l = l * corr + rsum;
    // rescale context (lane's acc rows are q' = 4g+r; corr lives at lane q')
    float c0 = __shfl(corr, 4 * g + 0);
    float c1 = __shfl(corr, 4 * g + 1);
    float c2 = __shfl(corr, 4 * g + 2);
    float c3 = __shfl(corr, 4 * g + 3);
    #pragma unroll
    for (int nt = 0; nt < 2; ++nt) {
      cc[nt][0] *= c0; cc[nt][1] *= c1; cc[nt][2] *= c2; cc[nt][3] *= c3;
    }
    // cross-lane RAW on Plds: HW-drain + compiler barrier
    asm volatile("s_waitcnt lgkmcnt(0)" ::: "memory");
    ushort8 pa0 = *(const ushort8*)(Pw + qi * PPAD + g * 8);
    ushort8 pa1 = *(const ushort8*)(Pw + qi * PPAD + 32 + g * 8);
    asm volatile("" ::: "memory");   // keep later P-stores after these loads
    #pragma unroll
    for (int nt = 0; nt < 2; ++nt) {
      cc[nt] = MFMA(pa0, vf[nt][0], cc[nt]);
      cc[nt] = MFMA(pa1, vf[nt][1], cc[nt]);
    }
  };

  auto finish = [&](const floatx4 (&cc)[2], float l, int tq) {
    float linv = 1.0f / l;
    float i0 = __shfl(linv, 4 * g + 0);
    float i1 = __shfl(linv, 4 * g + 1);
    float i2 = __shfl(linv, 4 * g + 2);
    float i3 = __shfl(linv, 4 * g + 3);
    #pragma unroll
    for (int nt = 0; nt < 2; ++nt) {
      int c = hh * 32 + nt * 16 + qi;
      int lq0 = tq * 64 + w * 16 + 4 * g;
      size_t base = ((size_t)bb * L_SEQ + lq0) * DMODEL + c;
      ctx[base + 0 * DMODEL] = f2bf(cc[nt][0] * i0);
      ctx[base + 1 * DMODEL] = f2bf(cc[nt][1] * i1);
      ctx[base + 2 * DMODEL] = f2bf(cc[nt][2] * i2);
      ctx[base + 3 * DMODEL] = f2bf(cc[nt][3] * i3);
    }
  };

  for (int t = 0; t <= tqb; ++t) {
    __syncthreads();
    // stage K tile [64][32] and V^T tile [32][64]
    *(ushort8*)(Klds + krow * KPAD + kch) =
        *(const ushort8*)(Kh + (size_t)(t * 64 + krow) * DHEAD + kch);
    *(ushort8*)(Vlds + vrow * VPAD + vch) =
        *(const ushort8*)(Vh + (size_t)vrow * L_SEQ + t * 64 + vch);
    __syncthreads();

    #pragma unroll
    for (int tt = 0; tt < 4; ++tt)
      kf[tt] = *(const ushort8*)(Klds + (tt * 16 + qi) * KPAD + g * 8);
    #pragma unroll
    for (int nt = 0; nt < 2; ++nt)
      #pragma unroll
      for (int kh = 0; kh < 2; ++kh)
        vf[nt][kh] = *(const ushort8*)(Vlds + (nt * 16 + qi) * VPAD + kh * 32 + g * 8);

    if (t <= tqa) step(qfa, ca, ma, la);
    step(qfb, cb, mb, lb);
  }

  finish(ca, la, tqa);
  finish(cb, lb, tqb);
}

// ---------------------------------------------------------------------------
// Kernel 3: output projection  out = ctx @ W_O^T + b_O  (f32 out)
// ---------------------------------------------------------------------------
__global__ __launch_bounds__(256) void oproj_kernel(
    const unsigned short* __restrict__ ctx, const float* __restrict__ WO,
    const float* __restrict__ bO, float* __restrict__ out)
{
  __shared__ unsigned short Wl[128 * WLDS];
  __shared__ float bl[128];
  const int m0 = blockIdx.x * 64;
  const int tid = threadIdx.x;

  #pragma unroll
  for (int it = 0; it < 16; ++it) {
    int idx = tid + it * 256;
    int row = idx >> 5, col = (idx & 31) * 4;
    floatx4 v = *(const floatx4*)(WO + row * 128 + col);
    unsigned short* dst = Wl + row * WLDS + col;
    dst[0] = f2bf(v[0]); dst[1] = f2bf(v[1]);
    dst[2] = f2bf(v[2]); dst[3] = f2bf(v[3]);
  }
  if (tid < 128) bl[tid] = bO[tid];
  __syncthreads();

  const int w = tid >> 6, lane = tid & 63;
  const int g = lane >> 4, qi = lane & 15;

  ushort8 xf[4];
  #pragma unroll
  for (int kk = 0; kk < 4; ++kk)
    xf[kk] = *(const ushort8*)(ctx + (size_t)(m0 + w * 16 + qi) * DMODEL + kk * 32 + g * 8);

  floatx4 acc[8];
  #pragma unroll
  for (int n = 0; n < 8; ++n) acc[n] = (floatx4){0.f, 0.f, 0.f, 0.f};

  #pragma unroll
  for (int kk = 0; kk < 4; ++kk) {
    #pragma unroll
    for (int n = 0; n < 8; ++n) {
      ushort8 wf = *(const ushort8*)(Wl + (n * 16 + qi) * WLDS + kk * 32 + g * 8);
      acc[n] = MFMA(xf[kk], wf, acc[n]);
    }
  }

  #pragma unroll
  for (int n = 0; n < 8; ++n) {
    int c = n * 16 + qi;
    float bb = bl[c];
    #pragma unroll
    for (int r = 0; r < 4; ++r) {
      int m = m0 + w * 16 + 4 * g + r;
      out[(size_t)m * DMODEL + c] = acc[n][r] + bb;
    }
  }
}

// ---------------------------------------------------------------------------
extern "C" void kernel_launch(void* const* d_in, const int* in_sizes, int n_in,
                              void* d_out, int out_size, void* d_ws, size_t ws_size,
                              hipStream_t stream) {
  const float* q  = (const float*)d_in[0];
  const float* k  = (const float*)d_in[1];
  const float* v  = (const float*)d_in[2];
  const float* WQ = (const float*)d_in[3];
  const float* bQ = (const float*)d_in[4];
  const float* WK = (const float*)d_in[5];
  const float* bK = (const float*)d_in[6];
  const float* WV = (const float*)d_in[7];
  const float* bV = (const float*)d_in[8];
  const float* WO = (const float*)d_in[9];
  const float* bO = (const float*)d_in[10];
  float* out = (float*)d_out;

  const size_t plane = (size_t)BATCH * NHEAD * L_SEQ * DHEAD;  // 1,048,576
  unsigned short* Qs  = (unsigned short*)d_ws;
  unsigned short* Ks  = Qs + plane;
  unsigned short* Vt  = Ks + plane;
  unsigned short* ctx = Vt + plane;   // [B][L][128] bf16

  hipLaunchKernelGGL(proj_kernel, dim3(64, 2, 3), dim3(256), 0, stream,
                     q, k, v, WQ, bQ, WK, bK, WV, bV, Qs, Ks, Vt);
  hipLaunchKernelGGL(attn_kernel, dim3(256), dim3(256), 0, stream, Qs, Ks, Vt, ctx);
  hipLaunchKernelGGL(oproj_kernel, dim3(128), dim3(256), 0, stream, ctx, WO, bO, out);
}